// Round 2
// baseline (1170.818 us; speedup 1.0000x reference)
//
#include <hip/hip_runtime.h>
#include <hip/hip_bf16.h>
#include <stdint.h>

typedef __attribute__((ext_vector_type(8))) short bf16x8;
typedef __attribute__((ext_vector_type(4))) float f32x4;

__device__ __forceinline__ unsigned short f2bf(float f) {
  union { float f; unsigned int u; } v; v.f = f;
  unsigned int u = v.u;
  u += 0x7fffu + ((u >> 16) & 1u);
  return (unsigned short)(u >> 16);
}

// ---------- X transform: [512,256,20,20] f32 -> Xt [512,400,256] bf16 ----------
__global__ __launch_bounds__(256) void xform_x(const float* __restrict__ X,
                                               unsigned short* __restrict__ Xt) {
  const int b = blockIdx.x;
  const int t = threadIdx.x;  // = ci
  const float* src = X + ((size_t)b * 256 + t) * 400;
  unsigned short* dst = Xt + (size_t)b * 400 * 256 + t;
  for (int hw = 0; hw < 400; hw += 4) {
    float4 v = *(const float4*)(src + hw);
    dst[(size_t)(hw + 0) * 256] = f2bf(v.x);
    dst[(size_t)(hw + 1) * 256] = f2bf(v.y);
    dst[(size_t)(hw + 2) * 256] = f2bf(v.z);
    dst[(size_t)(hw + 3) * 256] = f2bf(v.w);
  }
}

// ---------- W transform: [256co][256ci][81] f32 -> Wt [81][256co][256ci] bf16 ----------
__global__ __launch_bounds__(256) void xform_w(const float* __restrict__ W,
                                               unsigned short* __restrict__ Wt) {
  __shared__ unsigned short lds[81 * 128];
  const int co = blockIdx.x;       // 0..255
  const int ct = blockIdx.y;       // 0..1 (ci tile of 128)
  const int t = threadIdx.x;
  const float* src = W + ((size_t)co * 256 + (size_t)ct * 128) * 81;
  for (int idx = t; idx < 128 * 81; idx += 256) {
    int ci_l = idx / 81, khw = idx - ci_l * 81;
    lds[khw * 128 + ci_l] = f2bf(src[idx]);   // src read is fully linear
  }
  __syncthreads();
  unsigned short* dst = Wt + (size_t)co * 256 + (size_t)ct * 128;
  for (int idx = t; idx < 81 * 128; idx += 256) {
    int khw = idx >> 7, ci_l = idx & 127;
    dst[(size_t)khw * 65536 + ci_l] = lds[idx];  // coalesced 128-elem rows
  }
}

// ---------- implicit-GEMM conv + bias ----------
// M = 18432 (b,oh,ow), N = 256 (co), K = 81*256 in order (kh,kw,ci)
// BM=128 BN=64 BK=64, 4 waves (2x2), A: global->reg direct, B: LDS dbuf.
__device__ __forceinline__ void gload16(const unsigned short* g, unsigned short* l) {
  __builtin_amdgcn_global_load_lds(
      (const __attribute__((address_space(1))) unsigned int*)g,
      (__attribute__((address_space(3))) unsigned int*)l, 16, 0, 0);
}

__global__ __launch_bounds__(256, 2) void conv_gemm(
    const unsigned short* __restrict__ Xt,
    const unsigned short* __restrict__ Wt,
    const float* __restrict__ bias,
    float* __restrict__ Y) {
  __shared__ unsigned short sB[2 * 64 * 64];  // double-buffered, swizzled [co][ci]
  const int mt = blockIdx.x;   // 0..143
  const int nt = blockIdx.y;   // 0..3
  const int t = threadIdx.x;
  const int c8 = t & 7, rq = t >> 3;           // staging: 8 lanes/row, 32 rows/round
  const int swz = (c8 ^ (rq & 7)) * 8;         // pre-swizzled ci element offset

  // B stage source row bases (rows rq and rq+32 of the 64-co tile)
  const int wb0 = (nt * 64 + rq) * 256 + swz;
  const int wb1 = (nt * 64 + 32 + rq) * 256 + swz;
  unsigned short* ldsB = sB + t * 8;           // linear dest: byte = row*128 + c8*16

  const int lane = t & 63, wv = t >> 6;
  const int wm = (wv >> 1) * 64, wn = (wv & 1) * 32;
  const int l15 = lane & 15, l4 = lane >> 4, l7 = lane & 7;

  // A per-lane row bases (direct global loads; row = l&15, k-chunk = (l>>4)*8)
  int arow[4];
  #pragma unroll
  for (int i = 0; i < 4; ++i) {
    int m = mt * 128 + wm + i * 16 + l15;
    int b = m / 36, s = m - b * 36;
    int oh = s / 6, ow = s - oh * 6;
    arow[i] = ((b * 20 + 2 * oh) * 20 + 2 * ow) * 256 + l4 * 8;
  }

  // B fragment LDS element-offsets within one 4096-elem buffer (swizzle-matched)
  int pBo[2][2];
  #pragma unroll
  for (int j = 0; j < 2; ++j)
    #pragma unroll
    for (int kk = 0; kk < 2; ++kk)
      pBo[j][kk] = ((wn + j * 16 + l15) * 128 +
                    ((kk * 64 + l4 * 16) ^ (l7 << 4))) / 2;

  f32x4 acc[4][2];
  #pragma unroll
  for (int i = 0; i < 4; ++i)
    #pragma unroll
    for (int j = 0; j < 2; ++j) acc[i][j] = (f32x4){0.f, 0.f, 0.f, 0.f};

  bf16x8 afA[4][2], afB[4][2];

  // K-step offsets: step s -> khw = s>>2, ci0 = (s&3)*64
  // xo = (kh*20+kw)*256 + ci0 ; wo = khw*65536 + ci0  (SALU incremental)
  int s_ci = 0, s_kw = 0, xo = 0, wo = 0;
  auto adv = [&]() {
    if (s_ci < 3) { ++s_ci; xo += 64; wo += 64; }
    else {
      s_ci = 0; wo += 65536 - 192;
      if (s_kw < 8) { ++s_kw; xo += 64; }          // 256 - 192
      else          { s_kw = 0; xo += 2880; }      // 12*256 - 192
    }
  };
  auto loadA = [&](bf16x8 (&af)[4][2]) {
    #pragma unroll
    for (int i = 0; i < 4; ++i)
      #pragma unroll
      for (int kk = 0; kk < 2; ++kk)
        af[i][kk] = *(const bf16x8*)(Xt + arow[i] + xo + kk * 32);
  };
  auto stageB = [&](int bufo) {
    gload16(Wt + wo + wb0, ldsB + bufo);
    gload16(Wt + wo + wb1, ldsB + bufo + 2048);
  };
  auto compute = [&](const unsigned short* base, bf16x8 (&af)[4][2]) {
    bf16x8 bfr[2][2];
    #pragma unroll
    for (int j = 0; j < 2; ++j)
      #pragma unroll
      for (int kk = 0; kk < 2; ++kk)
        bfr[j][kk] = *(const bf16x8*)(base + pBo[j][kk]);
    #pragma unroll
    for (int i = 0; i < 4; ++i)
      #pragma unroll
      for (int j = 0; j < 2; ++j) {
        acc[i][j] = __builtin_amdgcn_mfma_f32_16x16x32_bf16(
            af[i][0], bfr[j][0], acc[i][j], 0, 0, 0);
        acc[i][j] = __builtin_amdgcn_mfma_f32_16x16x32_bf16(
            af[i][1], bfr[j][1], acc[i][j], 0, 0, 0);
      }
  };

  // prologue: stage step 0
  stageB(0);
  loadA(afA);
  adv();

  #pragma unroll 1
  for (int s = 0; s < 324; s += 2) {
    __syncthreads();                 // buf0 + afA for step s ready
    stageB(4096);                    // step s+1 -> buf1 (s+1 <= 323 always)
    loadA(afB);
    adv();
    compute(sB, afA);                // step s from buf0
    __syncthreads();                 // buf1 + afB for step s+1 ready
    if (s + 2 < 324) {
      stageB(0);                     // step s+2 -> buf0
      loadA(afA);
      adv();
    }
    compute(sB + 4096, afB);         // step s+1 from buf1
  }

  // epilogue: D row = (lane>>4)*4+q (m dim), col = lane&15 (co dim)
  #pragma unroll
  for (int j = 0; j < 2; ++j) {
    int co = nt * 64 + wn + j * 16 + l15;
    float bb = bias[co];
    #pragma unroll
    for (int i = 0; i < 4; ++i) {
      int m0 = mt * 128 + wm + i * 16 + l4 * 4;
      #pragma unroll
      for (int q = 0; q < 4; ++q) {
        int m = m0 + q;
        int b = m / 36, s = m - b * 36;
        Y[((size_t)b * 256 + co) * 36 + s] = acc[i][j][q] + bb;
      }
    }
  }
}

// ---------- squash (in place on d_out): groups of 8 consecutive floats ----------
__global__ __launch_bounds__(256) void squash_k(float* __restrict__ Y) {
  const int g = blockIdx.x * 256 + threadIdx.x;  // 0..589823
  float4* p = (float4*)(Y + (size_t)g * 8);
  float4 a = p[0], b = p[1];
  float ns = a.x * a.x + a.y * a.y + a.z * a.z + a.w * a.w +
             b.x * b.x + b.y * b.y + b.z * b.z + b.w * b.w;
  float sc = ns / ((1.0f + ns) * (0.001f + sqrtf(ns)));
  a.x *= sc; a.y *= sc; a.z *= sc; a.w *= sc;
  b.x *= sc; b.y *= sc; b.z *= sc; b.w *= sc;
  p[0] = a; p[1] = b;
}

extern "C" void kernel_launch(void* const* d_in, const int* in_sizes, int n_in,
                              void* d_out, int out_size, void* d_ws, size_t ws_size,
                              hipStream_t stream) {
  const float* X = (const float*)d_in[0];     // [512,256,20,20]
  const float* W = (const float*)d_in[1];     // [256,256,9,9]
  const float* bias = (const float*)d_in[2];  // [256]
  float* Y = (float*)d_out;                   // [512,256,6,6] -> squashed

  unsigned short* Xt = (unsigned short*)d_ws;                 // 512*400*256 bf16
  unsigned short* Wt = Xt + (size_t)512 * 400 * 256;          // 81*256*256 bf16

  xform_x<<<512, 256, 0, stream>>>(X, Xt);
  xform_w<<<dim3(256, 2), 256, 0, stream>>>(W, Wt);
  conv_gemm<<<dim3(144, 4), 256, 0, stream>>>(Xt, Wt, bias, Y);
  squash_k<<<2304, 256, 0, stream>>>(Y);
}

// Round 3
// 575.761 us; speedup vs baseline: 2.0335x; 2.0335x over previous
//
#include <hip/hip_runtime.h>
#include <hip/hip_bf16.h>
#include <stdint.h>

typedef __attribute__((ext_vector_type(8))) short bf16x8;
typedef __attribute__((ext_vector_type(4))) float f32x4;

__device__ __forceinline__ unsigned short f2bf(float f) {
  union { float f; unsigned int u; } v; v.f = f;
  unsigned int u = v.u;
  u += 0x7fffu + ((u >> 16) & 1u);
  return (unsigned short)(u >> 16);
}

// ---------- X transform: [512,256,20,20] f32 -> Xt [512,400,256] bf16 ----------
__global__ __launch_bounds__(256) void xform_x(const float* __restrict__ X,
                                               unsigned short* __restrict__ Xt) {
  const int b = blockIdx.x;
  const int t = threadIdx.x;  // = ci
  const float* src = X + ((size_t)b * 256 + t) * 400;
  unsigned short* dst = Xt + (size_t)b * 400 * 256 + t;
  for (int hw = 0; hw < 400; hw += 4) {
    float4 v = *(const float4*)(src + hw);
    dst[(size_t)(hw + 0) * 256] = f2bf(v.x);
    dst[(size_t)(hw + 1) * 256] = f2bf(v.y);
    dst[(size_t)(hw + 2) * 256] = f2bf(v.z);
    dst[(size_t)(hw + 3) * 256] = f2bf(v.w);
  }
}

// ---------- W transform: [256co][256ci][81] f32 -> Wt [81][256co][256ci] bf16 ----------
__global__ __launch_bounds__(256) void xform_w(const float* __restrict__ W,
                                               unsigned short* __restrict__ Wt) {
  __shared__ unsigned short lds[81 * 128];
  const int co = blockIdx.x;       // 0..255
  const int ct = blockIdx.y;       // 0..1 (ci tile of 128)
  const int t = threadIdx.x;
  const float* src = W + ((size_t)co * 256 + (size_t)ct * 128) * 81;
  for (int idx = t; idx < 128 * 81; idx += 256) {
    int ci_l = idx / 81, khw = idx - ci_l * 81;
    lds[khw * 128 + ci_l] = f2bf(src[idx]);   // src read is fully linear
  }
  __syncthreads();
  unsigned short* dst = Wt + (size_t)co * 256 + (size_t)ct * 128;
  for (int idx = t; idx < 81 * 128; idx += 256) {
    int khw = idx >> 7, ci_l = idx & 127;
    dst[(size_t)khw * 65536 + ci_l] = lds[idx];  // coalesced 128-elem rows
  }
}

// ---------- implicit-GEMM conv + bias ----------
// M = 18432 (b,oh,ow), N = 256 (co), K = 81*256 in order (kh,kw,ci)
// BM=64, BN=128, BK=32. 4 waves = 2 (K-halves) x 2 (co-halves); each wave
// computes a 64x64 tile (Rm=4, Rn=4) over its K-half; epilogue adds halves.
__device__ __forceinline__ void gload16(const unsigned short* g, unsigned short* l) {
  __builtin_amdgcn_global_load_lds(
      (const __attribute__((address_space(1))) unsigned int*)g,
      (__attribute__((address_space(3))) unsigned int*)l, 16, 0, 0);
}

__global__ __launch_bounds__(256, 3) void conv_gemm(
    const unsigned short* __restrict__ Xt,
    const unsigned short* __restrict__ Wt,
    const float* __restrict__ bias,
    float* __restrict__ Y) {
  // per buffer (12288 shorts): A [2ks][64row][32ci] = 4096, B [2ks][128co][32ci] = 8192
  __shared__ __align__(16) unsigned short lds[2 * 12288];  // 48 KB
  const int mt = blockIdx.x;   // 0..287
  const int nt = blockIdx.y;   // 0..1
  const int t = threadIdx.x;
  const int l = t & 63, w = t >> 6;
  const int wks = w >> 1;                 // this wave's K-half
  const int l15 = l & 15, l4 = l >> 4;
  const int sw = (l15 >> 1) & 3;          // 2-bit XOR swizzle

  // ---- staging: A 2 chunks/thread, B 4 chunks/thread (16 B each) ----
  int xsrcA[2], destA[2];
  #pragma unroll
  for (int r = 0; r < 2; ++r) {
    int row = (w & 1) * 32 + r * 16 + (l >> 2);
    int c4s = (l & 3) ^ ((row >> 1) & 3);
    int m = mt * 64 + row;
    int b = m / 36, sr = m - b * 36;
    int oh = sr / 6, ow = sr - oh * 6;
    xsrcA[r] = ((b * 20 + 2 * oh) * 20 + 2 * ow) * 256 + c4s * 8;
    destA[r] = (w * 128 + r * 64 + l) * 8;            // ks = w>>1 encoded in dc
  }
  int wsrcB[4], destB[4];
  #pragma unroll
  for (int r = 0; r < 4; ++r) {
    int co = (w & 1) * 64 + r * 16 + (l >> 2);
    int c4s = (l & 3) ^ ((co >> 1) & 3);
    wsrcB[r] = (nt * 128 + co) * 256 + c4s * 8;
    destB[r] = 4096 + (w * 256 + r * 64 + l) * 8;
  }

  // ---- fragment read offsets (element units, swizzle-matched, 2-way max) ----
  const int aoff = wks * 2048 + l15 * 32 + ((l4 ^ sw) * 8);
  const int boff = 4096 + wks * 4096 + ((w & 1) * 64 + l15) * 32 + ((l4 ^ sw) * 8);

  f32x4 acc[4][4];
  #pragma unroll
  for (int i = 0; i < 4; ++i)
    #pragma unroll
    for (int j = 0; j < 4; ++j) acc[i][j] = (f32x4){0.f, 0.f, 0.f, 0.f};

  // ---- wave-uniform K-walk state: gs = wks*324 + s; khw = gs>>3, ci0=(gs&7)*32
  int xo, wo, ci, kw;
  if (wks == 0) { xo = 0;     wo = 0;       ci = 0; kw = 0; }
  else          { xo = 21632; wo = 2621568; ci = 4; kw = 4; }  // gs=324: khw=40,ci0=128

  auto adv = [&]() {
    if (ci < 7) { ++ci; xo += 32; wo += 32; }
    else { ci = 0; wo += 65312;                    // 65536 - 224
           if (kw < 8) { ++kw; xo += 32; }         // 256 - 224
           else        { kw = 0; xo += 2848; } }   // 20*256 - 8*256 - 224
  };
  auto stage = [&](int p) {
    unsigned short* base = lds + p * 12288;
    #pragma unroll
    for (int r = 0; r < 2; ++r) gload16(Xt + xsrcA[r] + xo, base + destA[r]);
    #pragma unroll
    for (int r = 0; r < 4; ++r) gload16(Wt + wsrcB[r] + wo, base + destB[r]);
  };
  auto compute = [&](int p) {
    const unsigned short* base = lds + p * 12288;
    bf16x8 fa[4], fb[4];
    #pragma unroll
    for (int i = 0; i < 4; ++i) fa[i] = *(const bf16x8*)(base + aoff + i * 512);
    #pragma unroll
    for (int j = 0; j < 4; ++j) fb[j] = *(const bf16x8*)(base + boff + j * 512);
    #pragma unroll
    for (int i = 0; i < 4; ++i)
      #pragma unroll
      for (int j = 0; j < 4; ++j)
        acc[i][j] = __builtin_amdgcn_mfma_f32_16x16x32_bf16(fa[i], fb[j],
                                                            acc[i][j], 0, 0, 0);
  };

  stage(0); adv();
  int p = 0;
  #pragma unroll 1
  for (int s = 0; s < 324; ++s) {
    __syncthreads();                  // buf[p] staged; readers of buf[p^1] done
    if (s < 323) { stage(p ^ 1); adv(); }
    compute(p);
    p ^= 1;
  }

  // ---- epilogue: add K-halves across wave pairs (0<->2, 1<->3), + bias ----
  __syncthreads();
  f32x4* red = (f32x4*)lds;           // 2048 slots = 32 KB
  if (wks == 1) {
    #pragma unroll
    for (int i = 0; i < 4; ++i)
      #pragma unroll
      for (int j = 0; j < 4; ++j)
        red[(w & 1) * 1024 + (i * 4 + j) * 64 + l] = acc[i][j];
  }
  __syncthreads();
  if (wks == 0) {
    #pragma unroll
    for (int j = 0; j < 4; ++j) {
      int co = nt * 128 + (w & 1) * 64 + j * 16 + l15;
      float bb = bias[co];
      #pragma unroll
      for (int i = 0; i < 4; ++i) {
        f32x4 o = red[(w & 1) * 1024 + (i * 4 + j) * 64 + l];
        #pragma unroll
        for (int q = 0; q < 4; ++q) {
          int m = mt * 64 + i * 16 + l4 * 4 + q;
          int b = m / 36, sr = m - b * 36;
          Y[((size_t)b * 256 + co) * 36 + sr] = acc[i][j][q] + o[q] + bb;
        }
      }
    }
  }
}

// ---------- squash (in place on d_out): groups of 8 consecutive floats ----------
__global__ __launch_bounds__(256) void squash_k(float* __restrict__ Y) {
  const int g = blockIdx.x * 256 + threadIdx.x;  // 0..589823
  float4* p = (float4*)(Y + (size_t)g * 8);
  float4 a = p[0], b = p[1];
  float ns = a.x * a.x + a.y * a.y + a.z * a.z + a.w * a.w +
             b.x * b.x + b.y * b.y + b.z * b.z + b.w * b.w;
  float sc = ns / ((1.0f + ns) * (0.001f + sqrtf(ns)));
  a.x *= sc; a.y *= sc; a.z *= sc; a.w *= sc;
  b.x *= sc; b.y *= sc; b.z *= sc; b.w *= sc;
  p[0] = a; p[1] = b;
}

extern "C" void kernel_launch(void* const* d_in, const int* in_sizes, int n_in,
                              void* d_out, int out_size, void* d_ws, size_t ws_size,
                              hipStream_t stream) {
  const float* X = (const float*)d_in[0];     // [512,256,20,20]
  const float* W = (const float*)d_in[1];     // [256,256,9,9]
  const float* bias = (const float*)d_in[2];  // [256]
  float* Y = (float*)d_out;                   // [512,256,6,6] -> squashed

  unsigned short* Xt = (unsigned short*)d_ws;                 // 512*400*256 bf16
  unsigned short* Wt = Xt + (size_t)512 * 400 * 256;          // 81*256*256 bf16

  xform_x<<<512, 256, 0, stream>>>(X, Xt);
  xform_w<<<dim3(256, 2), 256, 0, stream>>>(W, Wt);
  conv_gemm<<<dim3(288, 2), 256, 0, stream>>>(Xt, Wt, bias, Y);
  squash_k<<<2304, 256, 0, stream>>>(Y);
}

// Round 5
// 505.361 us; speedup vs baseline: 2.3168x; 1.1393x over previous
//
#include <hip/hip_runtime.h>
#include <hip/hip_bf16.h>
#include <stdint.h>

typedef __attribute__((ext_vector_type(8))) short bf16x8;
typedef __attribute__((ext_vector_type(4))) float f32x4;

__device__ __forceinline__ unsigned short f2bf(float f) {
  union { float f; unsigned int u; } v; v.f = f;
  unsigned int u = v.u;
  u += 0x7fffu + ((u >> 16) & 1u);
  return (unsigned short)(u >> 16);
}

// ---------- X transform: [512,256,20,20] f32 -> Xt [512,400,256] bf16 ----------
__global__ __launch_bounds__(256) void xform_x(const float* __restrict__ X,
                                               unsigned short* __restrict__ Xt) {
  const int b = blockIdx.x;
  const int t = threadIdx.x;  // = ci
  const float* src = X + ((size_t)b * 256 + t) * 400;
  unsigned short* dst = Xt + (size_t)b * 400 * 256 + t;
  for (int hw = 0; hw < 400; hw += 4) {
    float4 v = *(const float4*)(src + hw);
    dst[(size_t)(hw + 0) * 256] = f2bf(v.x);
    dst[(size_t)(hw + 1) * 256] = f2bf(v.y);
    dst[(size_t)(hw + 2) * 256] = f2bf(v.z);
    dst[(size_t)(hw + 3) * 256] = f2bf(v.w);
  }
}

// ---------- W transform: [256co][256ci][81] f32 -> Wt [81][256co][256ci] bf16 ----------
__global__ __launch_bounds__(256) void xform_w(const float* __restrict__ W,
                                               unsigned short* __restrict__ Wt) {
  __shared__ unsigned short lds[81 * 128];
  const int co = blockIdx.x;       // 0..255
  const int ct = blockIdx.y;       // 0..1 (ci tile of 128)
  const int t = threadIdx.x;
  const float* src = W + ((size_t)co * 256 + (size_t)ct * 128) * 81;
  for (int idx = t; idx < 128 * 81; idx += 256) {
    int ci_l = idx / 81, khw = idx - ci_l * 81;
    lds[khw * 128 + ci_l] = f2bf(src[idx]);   // src read is fully linear
  }
  __syncthreads();
  unsigned short* dst = Wt + (size_t)co * 256 + (size_t)ct * 128;
  for (int idx = t; idx < 81 * 128; idx += 256) {
    int khw = idx >> 7, ci_l = idx & 127;
    dst[(size_t)khw * 65536 + ci_l] = lds[idx];  // coalesced 128-elem rows
  }
}

// ---------- implicit-GEMM conv + bias ----------
// M = 18432 (b,oh,ow), N = 256 (co), K = 81*256 in order (kh,kw,ci)
// BM=128 BN=64 BK=64, 4 waves (2x2). r1 structure + counted-vmcnt schedule.
// RACE FIX vs r4: every raw s_barrier is bracketed by sched_barrier(0) on
// BOTH sides — s_barrier is IntrNoMem in LLVM, so without the trailing
// sched_barrier the next stage()'s global_load_lds can hoist above the
// "all waves done reading buf[p]" barrier and overwrite a buffer another
// wave is still reading (post-timing divergence seen in r4).
__device__ __forceinline__ void gload16(const unsigned short* g, unsigned short* l) {
  __builtin_amdgcn_global_load_lds(
      (const __attribute__((address_space(1))) unsigned int*)g,
      (__attribute__((address_space(3))) unsigned int*)l, 16, 0, 0);
}

__global__ __launch_bounds__(256, 2) void conv_gemm(
    const unsigned short* __restrict__ Xt,
    const unsigned short* __restrict__ Wt,
    const float* __restrict__ bias,
    float* __restrict__ Y) {
  // per buffer (12288 shorts): A [128row][64ci] at 0, B [64co][64ci] at 8192
  __shared__ __align__(16) unsigned short lds[2][12288];  // 48 KB
  const int mt = blockIdx.x;   // 0..143
  const int nt = blockIdx.y;   // 0..3
  const int t = threadIdx.x;
  const int c8 = t & 7, rq = t >> 3;           // staging: 8 lanes/row, 32 rows/round
  const int swz = (c8 ^ (rq & 7)) * 8;         // pre-swizzled ci element offset

  // A staging sources (rows r*32+rq), incl. swizzle
  int xb[4];
  #pragma unroll
  for (int r = 0; r < 4; ++r) {
    int m = mt * 128 + r * 32 + rq;
    int b = m / 36, s = m - b * 36;
    int oh = s / 6, ow = s - oh * 6;
    xb[r] = ((b * 20 + 2 * oh) * 20 + 2 * ow) * 256 + swz;
  }
  int wb[2];
  #pragma unroll
  for (int r = 0; r < 2; ++r) wb[r] = (nt * 64 + r * 32 + rq) * 256 + swz;

  // staging dests within one buffer (elem units): linear, byte = row*128 + c8*16
  const int dA = t * 8;            // + r*2048
  const int dB = 8192 + t * 8;     // + r*2048

  const int lane = t & 63, wv = t >> 6;
  const int wm = (wv >> 1) * 64, wn = (wv & 1) * 32;
  const int l15 = lane & 15, l4 = lane >> 4, l7 = lane & 7;

  // fragment offsets within one buffer (elem units, swizzle-matched)
  int aOff[4][2], bOff[2][2];
  #pragma unroll
  for (int i = 0; i < 4; ++i)
    #pragma unroll
    for (int kk = 0; kk < 2; ++kk)
      aOff[i][kk] = ((wm + i * 16 + l15) * 128 +
                     ((kk * 64 + l4 * 16) ^ (l7 << 4))) / 2;
  #pragma unroll
  for (int j = 0; j < 2; ++j)
    #pragma unroll
    for (int kk = 0; kk < 2; ++kk)
      bOff[j][kk] = 8192 + ((wn + j * 16 + l15) * 128 +
                            ((kk * 64 + l4 * 16) ^ (l7 << 4))) / 2;

  f32x4 acc[4][2];
  #pragma unroll
  for (int i = 0; i < 4; ++i)
    #pragma unroll
    for (int j = 0; j < 2; ++j) acc[i][j] = (f32x4){0.f, 0.f, 0.f, 0.f};

  // K-step offsets: step s -> khw = s>>2, ci0 = (s&3)*64 (SALU incremental)
  int s_ci = 0, s_kw = 0, xo = 0, wo = 0;
  auto adv = [&]() {
    if (s_ci < 3) { ++s_ci; xo += 64; wo += 64; }
    else {
      s_ci = 0; wo += 65536 - 192;
      if (s_kw < 8) { ++s_kw; xo += 64; }          // 256 - 192
      else          { s_kw = 0; xo += 2880; }      // 12*256 - 192
    }
  };
  auto stage = [&](unsigned short* buf) {
    #pragma unroll
    for (int r = 0; r < 4; ++r) gload16(Xt + xb[r] + xo, buf + dA + r * 2048);
    #pragma unroll
    for (int r = 0; r < 2; ++r) gload16(Wt + wb[r] + wo, buf + dB + r * 2048);
  };
  auto compute = [&](const unsigned short* buf) {
    bf16x8 af[4][2], bfr[2][2];
    #pragma unroll
    for (int i = 0; i < 4; ++i)
      #pragma unroll
      for (int kk = 0; kk < 2; ++kk) af[i][kk] = *(const bf16x8*)(buf + aOff[i][kk]);
    #pragma unroll
    for (int j = 0; j < 2; ++j)
      #pragma unroll
      for (int kk = 0; kk < 2; ++kk) bfr[j][kk] = *(const bf16x8*)(buf + bOff[j][kk]);
    #pragma unroll
    for (int i = 0; i < 4; ++i)
      #pragma unroll
      for (int j = 0; j < 2; ++j) {
        acc[i][j] = __builtin_amdgcn_mfma_f32_16x16x32_bf16(
            af[i][0], bfr[j][0], acc[i][j], 0, 0, 0);
        acc[i][j] = __builtin_amdgcn_mfma_f32_16x16x32_bf16(
            af[i][1], bfr[j][1], acc[i][j], 0, 0, 0);
      }
  };

  stage(&lds[0][0]); adv();            // 6 loads in flight
  int p = 0;
  #pragma unroll 1
  for (int s = 0; s < 324; ++s) {
    if (s < 323) {
      stage(&lds[p ^ 1][0]); adv();    // +6 -> 12 in flight
      asm volatile("s_waitcnt vmcnt(6)" ::: "memory");  // step-s loads landed
    } else {
      asm volatile("s_waitcnt vmcnt(0)" ::: "memory");
    }
    __builtin_amdgcn_sched_barrier(0);
    __builtin_amdgcn_s_barrier();      // buf[p] visible to all waves
    __builtin_amdgcn_sched_barrier(0);
    __builtin_amdgcn_s_setprio(1);
    compute(&lds[p][0]);
    __builtin_amdgcn_s_setprio(0);
    __builtin_amdgcn_sched_barrier(0);
    __builtin_amdgcn_s_barrier();      // all waves done reading buf[p]
    __builtin_amdgcn_sched_barrier(0); // pin next stage AFTER this barrier
    p ^= 1;
  }

  // epilogue: D row = (lane>>4)*4+q (m dim), col = lane&15 (co dim)
  #pragma unroll
  for (int j = 0; j < 2; ++j) {
    int co = nt * 64 + wn + j * 16 + l15;
    float bb = bias[co];
    #pragma unroll
    for (int i = 0; i < 4; ++i) {
      int m0 = mt * 128 + wm + i * 16 + l4 * 4;
      #pragma unroll
      for (int q = 0; q < 4; ++q) {
        int m = m0 + q;
        int b = m / 36, s = m - b * 36;
        Y[((size_t)b * 256 + co) * 36 + s] = acc[i][j][q] + bb;
      }
    }
  }
}

// ---------- squash (in place on d_out): groups of 8 consecutive floats ----------
__global__ __launch_bounds__(256) void squash_k(float* __restrict__ Y) {
  const int g = blockIdx.x * 256 + threadIdx.x;  // 0..589823
  float4* p = (float4*)(Y + (size_t)g * 8);
  float4 a = p[0], b = p[1];
  float ns = a.x * a.x + a.y * a.y + a.z * a.z + a.w * a.w +
             b.x * b.x + b.y * b.y + b.z * b.z + b.w * b.w;
  float sc = ns / ((1.0f + ns) * (0.001f + sqrtf(ns)));
  a.x *= sc; a.y *= sc; a.z *= sc; a.w *= sc;
  b.x *= sc; b.y *= sc; b.z *= sc; b.w *= sc;
  p[0] = a; p[1] = b;
}

extern "C" void kernel_launch(void* const* d_in, const int* in_sizes, int n_in,
                              void* d_out, int out_size, void* d_ws, size_t ws_size,
                              hipStream_t stream) {
  const float* X = (const float*)d_in[0];     // [512,256,20,20]
  const float* W = (const float*)d_in[1];     // [256,256,9,9]
  const float* bias = (const float*)d_in[2];  // [256]
  float* Y = (float*)d_out;                   // [512,256,6,6] -> squashed

  unsigned short* Xt = (unsigned short*)d_ws;                 // 512*400*256 bf16
  unsigned short* Wt = Xt + (size_t)512 * 400 * 256;          // 81*256*256 bf16

  xform_x<<<512, 256, 0, stream>>>(X, Xt);
  xform_w<<<dim3(256, 2), 256, 0, stream>>>(W, Wt);
  conv_gemm<<<dim3(144, 4), 256, 0, stream>>>(Xt, Wt, bias, Y);
  squash_k<<<2304, 256, 0, stream>>>(Y);
}